// Round 19
// baseline (1651.251 us; speedup 1.0000x reference)
//
#include <hip/hip_runtime.h>

// Weighted furthest point sampling + gathers for KeypointDetector.
// B=16, N=16384, C=128, S=1024, SEM=20.
//
// FPS: one 512-thread block per batch (8 waves — halves barrier rendezvous
// cost vs 16), 32 points/thread, waves_per_eu(2,2) => 256-VGPR budget.
// Per step (lean R18 structure):
//   per-lane: update mind[k], track ONLY max score bs (1 inst/pt)
//   -> in-wave f32 max: 4 DPP xor-butterfly + row_bcast15/31 (all-VALU,
//      lane 63 = wave max) -> lane-63 leaders atomicMax(u32) into per-step
//      LDS slot -> barrier -> threads with bs==M rescan mind[k]*w[k]
//      bit-exactly for smallest matching k, atomicMin(n) -> barrier -> cur.
// 32-bit: value order == bit order (scores >= +0).
// Tie-break == numpy argmax: smallest n among score-max candidates.
//
// Output layout (float*, concatenated in reference return order):
//   [0, 49152)                  sampled_xyz      [B,S,3]
//   [49152, 49152+2097152)      sample_seg_feat  [B,C,S]
//   [2146304, 2162688)          sample_seg_label [B,S] (stored as float)

#define FPS_B   16
#define FPS_N   16384
#define FPS_C   128
#define FPS_S   1024
#define FPS_SEM 20
#define FPS_T   512
#define FPS_PPT 32   // points per thread = N / T

typedef unsigned long long ull;

// f32 lane permute via DPP (VALU-only). CTRL: 0xB1=xor1, 0x4E=xor2,
// 0x141=row_half_mirror (xor7 merge), 0x140=row_mirror (xor15 merge),
// 0x142=row_bcast15, 0x143=row_bcast31. bound_ctrl=1: sourceless lanes
// read 0 — harmless under fmax since all scores >= +0 and wave max > 0.
// Proven on HW in R10-R18 runs.
template <int CTRL>
__device__ __forceinline__ float dpp_movf(float v) {
  return __uint_as_float(__builtin_amdgcn_update_dpp(
      __float_as_uint(v), __float_as_uint(v), CTRL, 0xF, 0xF, true));
}

__global__ __launch_bounds__(FPS_T)
__attribute__((amdgpu_waves_per_eu(2, 2)))
void wfps_kernel(
    const float* __restrict__ xyz,    // [B,N,3]
    const int*   __restrict__ label,  // [B,N]
    int*         __restrict__ idx_out) // [B,S]
{
  const int b = blockIdx.x;
  const int t = threadIdx.x;
  const int lane = t & 63;

  __shared__ int counts[FPS_SEM];
  __shared__ unsigned wmax32[FPS_S];  // per-step max score bits (init 0)
  __shared__ int widx[FPS_S];         // per-step winner index (init MAX)

  if (t < FPS_SEM) counts[t] = 0;
  wmax32[t] = 0u;  wmax32[t + FPS_T] = 0u;        // T=512: two slots each
  widx[t] = 0x7FFFFFFF; widx[t + FPS_T] = 0x7FFFFFFF;
  __syncthreads();

  // ---- class-frequency weights ----
  const int* lab = label + b * FPS_N;
  int mylab[FPS_PPT];
#pragma unroll
  for (int k = 0; k < FPS_PPT; ++k) {
    mylab[k] = lab[t + k * FPS_T];
    atomicAdd(&counts[mylab[k]], 1);
  }
  __syncthreads();

  // ---- my 32 points in registers; n = t + k*512 ----
  const float* xb = xyz + b * FPS_N * 3;
  float px[FPS_PPT], py[FPS_PPT], pz[FPS_PPT], w[FPS_PPT], mind[FPS_PPT];
#pragma unroll
  for (int k = 0; k < FPS_PPT; ++k) {
    int n = t + k * FPS_T;
    px[k] = xb[n * 3 + 0];
    py[k] = xb[n * 3 + 1];
    pz[k] = xb[n * 3 + 2];
    w[k] = (float)counts[mylab[k]];
    mind[k] = 1e10f;
  }

  if (t == 0) idx_out[b * FPS_S] = 0;
  float lx = xb[0], ly = xb[1], lz = xb[2];

  // ---- serial FPS loop (unroll 2: halve loop-control overhead) ----
#pragma unroll 2
  for (int s = 1; s < FPS_S; ++s) {
    // per-lane: update mind, track max score ONLY (no index in hot loop)
    float bs = -1.0f;
#pragma unroll
    for (int k = 0; k < FPS_PPT; ++k) {
      // exact IEEE ops via _rn intrinsics: un-fusable, numpy summation order
      float dx = __fsub_rn(px[k], lx);
      float dy = __fsub_rn(py[k], ly);
      float dz = __fsub_rn(pz[k], lz);
      float d  = __fadd_rn(__fadd_rn(__fmul_rn(dx, dx), __fmul_rn(dy, dy)),
                           __fmul_rn(dz, dz));
      float m = fminf(mind[k], d);
      mind[k] = m;
      float sc = __fmul_rn(m, w[k]);
      bs = fmaxf(bs, sc);           // 1 inst/pt argmax-value tracking
    }

    // in-wave f32 max, ALL-VALU: xor butterfly to 16-groups, then
    // row_bcast15 + row_bcast31 cascade -> lane 63 holds the wave max.
    float m = bs;
    m = fmaxf(m, dpp_movf<0xB1>(m));
    m = fmaxf(m, dpp_movf<0x4E>(m));
    m = fmaxf(m, dpp_movf<0x141>(m));
    m = fmaxf(m, dpp_movf<0x140>(m));   // each 16-group reduced
    m = fmaxf(m, dpp_movf<0x142>(m));   // row1 |= g0, row3 |= g2
    m = fmaxf(m, dpp_movf<0x143>(m));   // lanes 32-63 |= max(g0,g1)

    if (lane == 63) atomicMax(&wmax32[s], __float_as_uint(m));
    __syncthreads();

    // phase 2: candidates (bs == BLOCK max; typically 1 thread -> ~1 wave
    // pays) recover smallest matching k by bit-exact register recompute
    // (descending overwrite), then race min-index.
    unsigned M = wmax32[s];
    if (__float_as_uint(bs) == M) {
      int bk = 0;
#pragma unroll
      for (int k = FPS_PPT - 1; k >= 0; --k)
        if (__float_as_uint(__fmul_rn(mind[k], w[k])) == M) bk = k;
      atomicMin(&widx[s], t + (bk << 9));   // n = t + k*512
    }
    __syncthreads();

    int cur = __builtin_amdgcn_readfirstlane(widx[s]);  // provably uniform
    if (t == 0) idx_out[b * FPS_S + s] = cur;

    // selected point coords: scalar/SMEM path (uniform address, cache-hot)
    const float* q = xb + 3 * cur;
    lx = q[0]; ly = q[1]; lz = q[2];
  }
}

// ---- gathers ----------------------------------------------------------------
__global__ void gather_kernel(
    const float* __restrict__ xyz,    // [B,N,3]
    const float* __restrict__ feat,   // [B,C,N]
    const int*   __restrict__ label,  // [B,N]
    const int*   __restrict__ idx,    // [B,S]
    float*       __restrict__ out)
{
  const long long FEAT = (long long)FPS_B * FPS_C * FPS_S;  // 2097152
  const int XYZN = FPS_B * FPS_S * 3;                       // 49152
  const int LABN = FPS_B * FPS_S;                           // 16384
  long long i = (long long)blockIdx.x * blockDim.x + threadIdx.x;

  if (i < FEAT) {
    int s = (int)(i & (FPS_S - 1));
    int c = (int)((i >> 10) & (FPS_C - 1));
    int b = (int)(i >> 17);
    int n = idx[b * FPS_S + s];
    out[XYZN + i] = feat[((long long)(b * FPS_C + c)) * FPS_N + n];
  } else if (i < FEAT + XYZN) {
    int j = (int)(i - FEAT);
    int d = j % 3;
    int sb = j / 3;
    int s = sb & (FPS_S - 1);
    int b = sb >> 10;
    int n = idx[b * FPS_S + s];
    out[j] = xyz[((long long)b * FPS_N + n) * 3 + d];
  } else if (i < FEAT + XYZN + LABN) {
    int j = (int)(i - FEAT - XYZN);
    int s = j & (FPS_S - 1);
    int b = j >> 10;
    int n = idx[b * FPS_S + s];
    out[FEAT + XYZN + j] = (float)label[b * FPS_N + n];
  }
}

extern "C" void kernel_launch(void* const* d_in, const int* in_sizes, int n_in,
                              void* d_out, int out_size, void* d_ws, size_t ws_size,
                              hipStream_t stream) {
  const float* xyz   = (const float*)d_in[0];
  const float* feat  = (const float*)d_in[1];
  const int*   label = (const int*)d_in[2];
  float* out = (float*)d_out;
  int*   idx = (int*)d_ws;  // B*S ints = 64 KiB scratch

  wfps_kernel<<<FPS_B, FPS_T, 0, stream>>>(xyz, label, idx);

  const long long total = (long long)FPS_B * FPS_C * FPS_S
                        + (long long)FPS_B * FPS_S * 3
                        + (long long)FPS_B * FPS_S;  // 2162688
  gather_kernel<<<(int)((total + 255) / 256), 256, 0, stream>>>(
      xyz, feat, label, idx, out);
}

// Round 21
// 1519.871 us; speedup vs baseline: 1.0864x; 1.0864x over previous
//
#include <hip/hip_runtime.h>

// Weighted furthest point sampling + gathers for KeypointDetector.
// B=16, N=16384, C=128, S=1024, SEM=20.
//
// FPS: one 1024-thread block per batch (R18 structure, scalar IEEE math —
// v_pk_*_f32 proven non-bit-identical on this chip in R3/R5/R20). Per step:
//   per-lane: update mind[k], track ONLY max score bs (v_max3 pairing)
//   -> in-wave f32 max (4 DPP xor-butterfly + row_bcast15/31, lane 63)
//   -> lane-63 leaders ds_write wave max to per-wave slot wvmax[wave]
//      (parallel plain stores — replaces 16 serialized atomicMax to one
//       address) -> barrier -> all lanes read wvmax[lane&15] + 4 DPP
//      levels -> block max M in-register for every lane
//   -> candidates (bs==M) rescan mind[k]*w[k] bit-exactly for smallest
//      matching k, atomicMin(n) into widx[s] -> barrier -> cur.
// Slot safety: wvmax written pre-barrier-1, read pre-barrier-2, next write
// post-barrier-2 — the step's two barriers fence it; no double-buffer.
// 32-bit: value order == bit order (scores >= +0).
// Tie-break == numpy argmax: smallest n among score-max candidates.
//
// Output layout (float*, concatenated in reference return order):
//   [0, 49152)                  sampled_xyz      [B,S,3]
//   [49152, 49152+2097152)      sample_seg_feat  [B,C,S]
//   [2146304, 2162688)          sample_seg_label [B,S] (stored as float)

#define FPS_B   16
#define FPS_N   16384
#define FPS_C   128
#define FPS_S   1024
#define FPS_SEM 20
#define FPS_T   1024
#define FPS_PPT 16   // points per thread = N / T

typedef unsigned long long ull;

// f32 lane permute via DPP (VALU-only). CTRL: 0xB1=xor1, 0x4E=xor2,
// 0x141=row_half_mirror, 0x140=row_mirror (these 4 reduce each 16-group),
// 0x142=row_bcast15, 0x143=row_bcast31 (cascade 16-group maxes to lane 63).
// bound_ctrl=1: sourceless lanes read 0 — harmless under fmax (scores >= +0).
// Proven on HW in R10-R19 runs.
template <int CTRL>
__device__ __forceinline__ float dpp_movf(float v) {
  return __uint_as_float(__builtin_amdgcn_update_dpp(
      __float_as_uint(v), __float_as_uint(v), CTRL, 0xF, 0xF, true));
}

__global__ __launch_bounds__(FPS_T)
__attribute__((amdgpu_waves_per_eu(4, 4)))
void wfps_kernel(
    const float* __restrict__ xyz,    // [B,N,3]
    const int*   __restrict__ label,  // [B,N]
    int*         __restrict__ idx_out) // [B,S]
{
  const int b = blockIdx.x;
  const int t = threadIdx.x;
  const int lane = t & 63;
  const int wave = t >> 6;

  __shared__ int counts[FPS_SEM];
  __shared__ float wvmax[16];   // per-wave max, rewritten every step
  __shared__ int widx[FPS_S];   // per-step winner index (init MAX, single-use)

  if (t < FPS_SEM) counts[t] = 0;
  widx[t] = 0x7FFFFFFF;      // T == FPS_S: each thread inits one slot
  __syncthreads();

  // ---- class-frequency weights ----
  const int* lab = label + b * FPS_N;
  int mylab[FPS_PPT];
#pragma unroll
  for (int k = 0; k < FPS_PPT; ++k) {
    mylab[k] = lab[t + k * FPS_T];
    atomicAdd(&counts[mylab[k]], 1);
  }
  __syncthreads();

  // ---- my 16 points in registers; n = t + k*1024 ----
  const float* xb = xyz + b * FPS_N * 3;
  float px[FPS_PPT], py[FPS_PPT], pz[FPS_PPT], w[FPS_PPT], mind[FPS_PPT];
#pragma unroll
  for (int k = 0; k < FPS_PPT; ++k) {
    int n = t + k * FPS_T;
    px[k] = xb[n * 3 + 0];
    py[k] = xb[n * 3 + 1];
    pz[k] = xb[n * 3 + 2];
    w[k] = (float)counts[mylab[k]];
    mind[k] = 1e10f;
    asm("" : "+v"(px[k]), "+v"(py[k]), "+v"(pz[k]), "+v"(w[k]));
  }

  if (t == 0) idx_out[b * FPS_S] = 0;
  float lx = xb[0], ly = xb[1], lz = xb[2];

  // ---- serial FPS loop (unroll 2: halve loop-control overhead) ----
#pragma unroll 2
  for (int s = 1; s < FPS_S; ++s) {
    // per-lane: update mind, track max score ONLY (no index in hot loop).
    // Scores paired so fmaxf(fmaxf(bs,sc0),sc1) folds to v_max3_f32 —
    // max is order-invariant on NaN-free values; index found in phase 2.
    float bs = -1.0f;
#pragma unroll
    for (int k = 0; k < FPS_PPT; k += 2) {
      // exact IEEE ops via _rn intrinsics: un-fusable, numpy summation order
      float dx0 = __fsub_rn(px[k], lx);
      float dy0 = __fsub_rn(py[k], ly);
      float dz0 = __fsub_rn(pz[k], lz);
      float d0  = __fadd_rn(__fadd_rn(__fmul_rn(dx0, dx0), __fmul_rn(dy0, dy0)),
                            __fmul_rn(dz0, dz0));
      float m0 = fminf(mind[k], d0);
      mind[k] = m0;
      float sc0 = __fmul_rn(m0, w[k]);

      float dx1 = __fsub_rn(px[k + 1], lx);
      float dy1 = __fsub_rn(py[k + 1], ly);
      float dz1 = __fsub_rn(pz[k + 1], lz);
      float d1  = __fadd_rn(__fadd_rn(__fmul_rn(dx1, dx1), __fmul_rn(dy1, dy1)),
                            __fmul_rn(dz1, dz1));
      float m1 = fminf(mind[k + 1], d1);
      mind[k + 1] = m1;
      float sc1 = __fmul_rn(m1, w[k + 1]);

      bs = fmaxf(fmaxf(bs, sc0), sc1);   // v_max3_f32
    }

    // in-wave f32 max, ALL-VALU: butterfly + bcast cascade -> lane 63.
    float m = bs;
    m = fmaxf(m, dpp_movf<0xB1>(m));
    m = fmaxf(m, dpp_movf<0x4E>(m));
    m = fmaxf(m, dpp_movf<0x141>(m));
    m = fmaxf(m, dpp_movf<0x140>(m));   // each 16-group reduced
    m = fmaxf(m, dpp_movf<0x142>(m));   // row1 |= g0, row3 |= g2
    m = fmaxf(m, dpp_movf<0x143>(m));   // lane 63 = wave max

    if (lane == 63) wvmax[wave] = m;    // plain parallel store, no atomic
    __syncthreads();

    // block max: one broadcast-friendly LDS read + 4 DPP levels, in-register
    float M = wvmax[lane & 15];
    M = fmaxf(M, dpp_movf<0xB1>(M));
    M = fmaxf(M, dpp_movf<0x4E>(M));
    M = fmaxf(M, dpp_movf<0x141>(M));
    M = fmaxf(M, dpp_movf<0x140>(M));   // all lanes now hold block max

    // phase 2: candidates (bs == block max; typically 1 thread -> ~1 wave
    // pays) recover smallest matching k by bit-exact register recompute
    // (descending overwrite), then race min-index.
    unsigned Mbits = __float_as_uint(M);
    if (__float_as_uint(bs) == Mbits) {
      int bk = 0;
#pragma unroll
      for (int k = FPS_PPT - 1; k >= 0; --k)
        if (__float_as_uint(__fmul_rn(mind[k], w[k])) == Mbits) bk = k;
      atomicMin(&widx[s], t + (bk << 10));   // n = t + k*1024
    }
    __syncthreads();

    int cur = __builtin_amdgcn_readfirstlane(widx[s]);  // provably uniform
    if (t == 0) idx_out[b * FPS_S + s] = cur;

    // selected point coords: scalar/SMEM path (uniform address, cache-hot)
    const float* q = xb + 3 * cur;
    lx = q[0]; ly = q[1]; lz = q[2];
  }
}

// ---- gathers ----------------------------------------------------------------
__global__ void gather_kernel(
    const float* __restrict__ xyz,    // [B,N,3]
    const float* __restrict__ feat,   // [B,C,N]
    const int*   __restrict__ label,  // [B,N]
    const int*   __restrict__ idx,    // [B,S]
    float*       __restrict__ out)
{
  const long long FEAT = (long long)FPS_B * FPS_C * FPS_S;  // 2097152
  const int XYZN = FPS_B * FPS_S * 3;                       // 49152
  const int LABN = FPS_B * FPS_S;                           // 16384
  long long i = (long long)blockIdx.x * blockDim.x + threadIdx.x;

  if (i < FEAT) {
    int s = (int)(i & (FPS_S - 1));
    int c = (int)((i >> 10) & (FPS_C - 1));
    int b = (int)(i >> 17);
    int n = idx[b * FPS_S + s];
    out[XYZN + i] = feat[((long long)(b * FPS_C + c)) * FPS_N + n];
  } else if (i < FEAT + XYZN) {
    int j = (int)(i - FEAT);
    int d = j % 3;
    int sb = j / 3;
    int s = sb & (FPS_S - 1);
    int b = sb >> 10;
    int n = idx[b * FPS_S + s];
    out[j] = xyz[((long long)b * FPS_N + n) * 3 + d];
  } else if (i < FEAT + XYZN + LABN) {
    int j = (int)(i - FEAT - XYZN);
    int s = j & (FPS_S - 1);
    int b = j >> 10;
    int n = idx[b * FPS_S + s];
    out[FEAT + XYZN + j] = (float)label[b * FPS_N + n];
  }
}

extern "C" void kernel_launch(void* const* d_in, const int* in_sizes, int n_in,
                              void* d_out, int out_size, void* d_ws, size_t ws_size,
                              hipStream_t stream) {
  const float* xyz   = (const float*)d_in[0];
  const float* feat  = (const float*)d_in[1];
  const int*   label = (const int*)d_in[2];
  float* out = (float*)d_out;
  int*   idx = (int*)d_ws;  // B*S ints = 64 KiB scratch

  wfps_kernel<<<FPS_B, FPS_T, 0, stream>>>(xyz, label, idx);

  const long long total = (long long)FPS_B * FPS_C * FPS_S
                        + (long long)FPS_B * FPS_S * 3
                        + (long long)FPS_B * FPS_S;  // 2162688
  gather_kernel<<<(int)((total + 255) / 256), 256, 0, stream>>>(
      xyz, feat, label, idx, out);
}